// Round 1
// 1046.799 us; speedup vs baseline: 1.0196x; 1.0196x over previous
//
#include <hip/hip_runtime.h>

// NeuralTS: out = MLP(concat(x_user @ W_w.T, gather(H_w.T, x_item)))
// Dominated by streaming x_user (819.2 MB) once -> HBM-bound, floor ~130 us.
//
// R1 theory: previous gemv ran ~520 us (~1.6 TB/s) because W_w (2.4 MB) was
// re-read by all 512 row-groups (1.2 GB) and thrashed out of L2 by the x_user
// stream. Fixes: (a) NCHUNK=8 with chunk as fastest-varying blockIdx ->
// chunk c lands on XCD c (round-robin dispatch), W working set per XCD =
// 300 KB, L2-resident; (b) non-temporal loads for the read-once x_user
// stream so it doesn't evict W; (c) MTILE=8 halves W read traffic.

#define NUSERS  100000
#define NITEMS  100000
#define BATCH   2048
#define EMBK    6
#define N4      (NUSERS / 4)     // 25000 float4 per row
#define MTILE   8                // batch rows per block
#define NCHUNK  8                // == #XCDs: chunk c -> XCD c via dispatch round-robin
#define THREADS 256
#define CHUNK4  (N4 / NCHUNK)    // 3125 float4 per chunk

typedef float f32x4 __attribute__((ext_vector_type(4)));

// Phase 1: partial dot-products of x_user rows with the 6 W_w rows.
// Grid: (NCHUNK, BATCH/MTILE). Each block owns MTILE rows x one n-chunk.
__global__ __launch_bounds__(THREADS, 4)
void gemv_partial(const float* __restrict__ x_user,
                  const float* __restrict__ W_w,
                  float* __restrict__ partial)
{
    const int c   = blockIdx.x;            // chunk index == target XCD
    const int m0  = blockIdx.y * MTILE;
    const int tid = threadIdx.x;

    float acc[MTILE][EMBK];
#pragma unroll
    for (int m = 0; m < MTILE; ++m)
#pragma unroll
        for (int k = 0; k < EMBK; ++k) acc[m][k] = 0.f;

    const f32x4* __restrict__ W4 = (const f32x4*)W_w;
    const f32x4* __restrict__ X4 = (const f32x4*)x_user;

    const int jEnd = (c + 1) * CHUNK4;
    for (int j = c * CHUNK4 + tid; j < jEnd; j += THREADS) {
        f32x4 w[EMBK];
#pragma unroll
        for (int k = 0; k < EMBK; ++k) w[k] = W4[k * N4 + j];   // L2-resident
#pragma unroll
        for (int m = 0; m < MTILE; ++m) {
            // read-once stream: nt load, bypass/age-out L2 so W stays hot
            const f32x4 x =
                __builtin_nontemporal_load(&X4[(size_t)(m0 + m) * N4 + j]);
#pragma unroll
            for (int k = 0; k < EMBK; ++k)
                acc[m][k] += x.x * w[k].x + x.y * w[k].y
                           + x.z * w[k].z + x.w * w[k].w;
        }
    }

    // Intra-wave butterfly reduction of the 48 accumulators.
#pragma unroll
    for (int m = 0; m < MTILE; ++m)
#pragma unroll
        for (int k = 0; k < EMBK; ++k) {
            float v = acc[m][k];
#pragma unroll
            for (int off = 32; off > 0; off >>= 1)
                v += __shfl_down(v, off, 64);
            acc[m][k] = v;
        }

    // Cross-wave reduction through LDS (4 waves).
    __shared__ float red[THREADS / 64][MTILE * EMBK];
    const int wave = tid >> 6, lane = tid & 63;
    if (lane == 0) {
#pragma unroll
        for (int m = 0; m < MTILE; ++m)
#pragma unroll
            for (int k = 0; k < EMBK; ++k)
                red[wave][m * EMBK + k] = acc[m][k];
    }
    __syncthreads();
    if (tid < MTILE * EMBK) {
        float s = 0.f;
#pragma unroll
        for (int w = 0; w < THREADS / 64; ++w) s += red[w][tid];
        const int m = tid / EMBK, k = tid % EMBK;
        partial[((size_t)c * BATCH + (m0 + m)) * EMBK + k] = s;
    }
}

// Phase 2: reduce the NCHUNK partials, gather item embedding, run the MLP.
__global__ __launch_bounds__(256)
void finish(const float* __restrict__ partial,
            const int*   __restrict__ x_item,
            const float* __restrict__ H_w,
            const float* __restrict__ W1, const float* __restrict__ b1,
            const float* __restrict__ W2, const float* __restrict__ b2,
            const float* __restrict__ W3,
            float* __restrict__ out)
{
    const int b = blockIdx.x * blockDim.x + threadIdx.x;
    if (b >= BATCH) return;

    float z[12];
#pragma unroll
    for (int k = 0; k < EMBK; ++k) {
        float s = 0.f;
#pragma unroll
        for (int c = 0; c < NCHUNK; ++c)
            s += partial[((size_t)c * BATCH + b) * EMBK + k];
        z[k] = s;
    }

    const int item = x_item[b];
#pragma unroll
    for (int k = 0; k < EMBK; ++k)
        z[EMBK + k] = H_w[(size_t)k * NITEMS + item];

    float h1[16];
#pragma unroll
    for (int j = 0; j < 16; ++j) {
        float s = b1[j];
#pragma unroll
        for (int i = 0; i < 12; ++i) s += W1[j * 12 + i] * z[i];
        h1[j] = fmaxf(s, 0.f);
    }

    float h2[8];
#pragma unroll
    for (int j = 0; j < 8; ++j) {
        float s = b2[j];
#pragma unroll
        for (int i = 0; i < 16; ++i) s += W2[j * 16 + i] * h1[i];
        h2[j] = fmaxf(s, 0.f);
    }

    float o = W3[8];  // bias via the appended ones-column
#pragma unroll
    for (int j = 0; j < 8; ++j) o += W3[j] * h2[j];
    out[b] = o;
}

extern "C" void kernel_launch(void* const* d_in, const int* in_sizes, int n_in,
                              void* d_out, int out_size, void* d_ws, size_t ws_size,
                              hipStream_t stream)
{
    const float* x_user = (const float*)d_in[0];
    const int*   x_item = (const int*)  d_in[1];
    const float* W_w    = (const float*)d_in[2];
    const float* H_w    = (const float*)d_in[3];
    const float* W1     = (const float*)d_in[4];
    const float* b1     = (const float*)d_in[5];
    const float* W2     = (const float*)d_in[6];
    const float* b2     = (const float*)d_in[7];
    const float* W3     = (const float*)d_in[8];
    float*       out    = (float*)d_out;
    float*       partial = (float*)d_ws;   // NCHUNK*BATCH*EMBK*4 = 384 KB

    dim3 grid1(NCHUNK, BATCH / MTILE);
    gemv_partial<<<grid1, THREADS, 0, stream>>>(x_user, W_w, partial);
    finish<<<(BATCH + 255) / 256, 256, 0, stream>>>(partial, x_item, H_w,
                                                    W1, b1, W2, b2, W3, out);
}

// Round 2
// 1005.065 us; speedup vs baseline: 1.0619x; 1.0415x over previous
//
#include <hip/hip_runtime.h>

// NeuralTS: out = MLP(concat(x_user @ W_w.T, gather(H_w.T, x_item)))
// Dominated by streaming x_user (819.2 MB) once -> HBM-bound, floor ~130 us.
//
// R2 probe: R1's __launch_bounds__(256,4) capped VGPRs at 128 while MTILE=8
// needs ~120-135 -> possible scratch spill (hidden HBM traffic) that would
// explain gemv sitting ~4x above its 150 us memory floor. This round removes
// the cap (one variable). Also: X loads (HBM, ~900 cy) issued before W loads
// (L2-hit) so the long-latency stream starts first.

#define NUSERS  100000
#define NITEMS  100000
#define BATCH   2048
#define EMBK    6
#define N4      (NUSERS / 4)     // 25000 float4 per row
#define MTILE   8                // batch rows per block
#define NCHUNK  8                // == #XCDs: chunk c -> XCD c via dispatch round-robin
#define THREADS 256
#define CHUNK4  (N4 / NCHUNK)    // 3125 float4 per chunk

typedef float f32x4 __attribute__((ext_vector_type(4)));

// Phase 1: partial dot-products of x_user rows with the 6 W_w rows.
// Grid: (NCHUNK, BATCH/MTILE). Each block owns MTILE rows x one n-chunk.
// NOTE: no min-waves clause -> VGPR cap 256, spill-free guaranteed.
__global__ __launch_bounds__(THREADS)
void gemv_partial(const float* __restrict__ x_user,
                  const float* __restrict__ W_w,
                  float* __restrict__ partial)
{
    const int c   = blockIdx.x;            // chunk index == target XCD
    const int m0  = blockIdx.y * MTILE;
    const int tid = threadIdx.x;

    float acc[MTILE][EMBK];
#pragma unroll
    for (int m = 0; m < MTILE; ++m)
#pragma unroll
        for (int k = 0; k < EMBK; ++k) acc[m][k] = 0.f;

    const f32x4* __restrict__ W4 = (const f32x4*)W_w;
    const f32x4* __restrict__ X4 = (const f32x4*)x_user;

    const int jEnd = (c + 1) * CHUNK4;
    for (int j = c * CHUNK4 + tid; j < jEnd; j += THREADS) {
        // Issue the long-latency HBM stream first (read-once -> nt).
        f32x4 x[MTILE];
#pragma unroll
        for (int m = 0; m < MTILE; ++m)
            x[m] = __builtin_nontemporal_load(&X4[(size_t)(m0 + m) * N4 + j]);

        // W chunk (300 KB/XCD) is L2-resident; short-latency loads second.
        f32x4 w[EMBK];
#pragma unroll
        for (int k = 0; k < EMBK; ++k) w[k] = W4[k * N4 + j];

#pragma unroll
        for (int m = 0; m < MTILE; ++m)
#pragma unroll
            for (int k = 0; k < EMBK; ++k)
                acc[m][k] += x[m].x * w[k].x + x[m].y * w[k].y
                           + x[m].z * w[k].z + x[m].w * w[k].w;
    }

    // Intra-wave butterfly reduction of the 48 accumulators.
#pragma unroll
    for (int m = 0; m < MTILE; ++m)
#pragma unroll
        for (int k = 0; k < EMBK; ++k) {
            float v = acc[m][k];
#pragma unroll
            for (int off = 32; off > 0; off >>= 1)
                v += __shfl_down(v, off, 64);
            acc[m][k] = v;
        }

    // Cross-wave reduction through LDS (4 waves).
    __shared__ float red[THREADS / 64][MTILE * EMBK];
    const int wave = tid >> 6, lane = tid & 63;
    if (lane == 0) {
#pragma unroll
        for (int m = 0; m < MTILE; ++m)
#pragma unroll
            for (int k = 0; k < EMBK; ++k)
                red[wave][m * EMBK + k] = acc[m][k];
    }
    __syncthreads();
    if (tid < MTILE * EMBK) {
        float s = 0.f;
#pragma unroll
        for (int w = 0; w < THREADS / 64; ++w) s += red[w][tid];
        const int m = tid / EMBK, k = tid % EMBK;
        partial[((size_t)c * BATCH + (m0 + m)) * EMBK + k] = s;
    }
}

// Phase 2: reduce the NCHUNK partials, gather item embedding, run the MLP.
__global__ __launch_bounds__(256)
void finish(const float* __restrict__ partial,
            const int*   __restrict__ x_item,
            const float* __restrict__ H_w,
            const float* __restrict__ W1, const float* __restrict__ b1,
            const float* __restrict__ W2, const float* __restrict__ b2,
            const float* __restrict__ W3,
            float* __restrict__ out)
{
    const int b = blockIdx.x * blockDim.x + threadIdx.x;
    if (b >= BATCH) return;

    float z[12];
#pragma unroll
    for (int k = 0; k < EMBK; ++k) {
        float s = 0.f;
#pragma unroll
        for (int c = 0; c < NCHUNK; ++c)
            s += partial[((size_t)c * BATCH + b) * EMBK + k];
        z[k] = s;
    }

    const int item = x_item[b];
#pragma unroll
    for (int k = 0; k < EMBK; ++k)
        z[EMBK + k] = H_w[(size_t)k * NITEMS + item];

    float h1[16];
#pragma unroll
    for (int j = 0; j < 16; ++j) {
        float s = b1[j];
#pragma unroll
        for (int i = 0; i < 12; ++i) s += W1[j * 12 + i] * z[i];
        h1[j] = fmaxf(s, 0.f);
    }

    float h2[8];
#pragma unroll
    for (int j = 0; j < 8; ++j) {
        float s = b2[j];
#pragma unroll
        for (int i = 0; i < 16; ++i) s += W2[j * 16 + i] * h1[i];
        h2[j] = fmaxf(s, 0.f);
    }

    float o = W3[8];  // bias via the appended ones-column
#pragma unroll
    for (int j = 0; j < 8; ++j) o += W3[j] * h2[j];
    out[b] = o;
}

extern "C" void kernel_launch(void* const* d_in, const int* in_sizes, int n_in,
                              void* d_out, int out_size, void* d_ws, size_t ws_size,
                              hipStream_t stream)
{
    const float* x_user = (const float*)d_in[0];
    const int*   x_item = (const int*)  d_in[1];
    const float* W_w    = (const float*)d_in[2];
    const float* H_w    = (const float*)d_in[3];
    const float* W1     = (const float*)d_in[4];
    const float* b1     = (const float*)d_in[5];
    const float* W2     = (const float*)d_in[6];
    const float* b2     = (const float*)d_in[7];
    const float* W3     = (const float*)d_in[8];
    float*       out    = (float*)d_out;
    float*       partial = (float*)d_ws;   // NCHUNK*BATCH*EMBK*4 = 384 KB

    dim3 grid1(NCHUNK, BATCH / MTILE);
    gemv_partial<<<grid1, THREADS, 0, stream>>>(x_user, W_w, partial);
    finish<<<(BATCH + 255) / 256, 256, 0, stream>>>(partial, x_item, H_w,
                                                    W1, b1, W2, b2, W3, out);
}